// Round 10
// baseline (2468.082 us; speedup 1.0000x reference)
//
#include <hip/hip_runtime.h>
#include <hip/hip_bf16.h>
#include <math.h>

// Buggy flash-attn fwd (no acc rescale, running-l division) per 64-wide KV
// block. B=2 H=16 S=4096 D=128, fp32 in/out, bf16 MFMA compute.
// Round 10: revert T15 (neutral); LDS shrunk to exactly 64KB via XOR-swizzled
// K [64][128] (^16*(row&7) bytes) and V [128][64] (^16*(d&7) bytes) so TWO
// WGs co-reside per CU (128KB apparent limit; round 3 precedent at 54KB->45%
// occ). New V staging map (nq=tid&15, dq=tid>>4) keeps global loads 64B-line
// efficient and makes V writes bank-conflict-free. Compute structure and all
// fragment semantics bit-identical to round 8.

typedef __attribute__((ext_vector_type(8)))  unsigned short ushort8;
typedef __attribute__((ext_vector_type(8)))  __bf16        bf16x8;
typedef __attribute__((ext_vector_type(16))) float         f32x16;
typedef __attribute__((ext_vector_type(4)))  float         floatv4;
typedef __attribute__((ext_vector_type(2)))  unsigned int  uint2v;
typedef __attribute__((ext_vector_type(4)))  unsigned int  uint4v;

#define SQ   4096
#define SKV  4096
#define DH   128
#define BN   64
#define QB   256
#define NT   (SKV / BN)   // 64
#define KROW 128          // K row stride (elems), no pad; XOR swizzle instead
#define VROW 64           // Vt row stride (elems), no pad; XOR swizzle instead
#define KBUF (64 * KROW)  // 8192 elems = 16KB
#define VBUF (DH * VROW)  // 8192 elems = 16KB

// packed f32x2 -> bf16x2 word: single v_cvt_pk_bf16_f32 (RNE)
static __device__ __forceinline__ unsigned pk2(float lo, float hi) {
    unsigned r;
    asm("v_cvt_pk_bf16_f32 %0, %1, %2" : "=v"(r) : "v"(lo), "v"(hi));
    return r;
}

__global__ __launch_bounds__(512, 4) void fa_fwd_buggy(
    const float* __restrict__ Qg, const float* __restrict__ Kg,
    const float* __restrict__ Vg, float* __restrict__ Og)
{
    // LDS: 2 x (K 16KB + Vt 16KB) = 65536 B exactly -> 2 WGs/CU.
    __shared__ unsigned short K_lds[2 * KBUF];
    __shared__ unsigned short Vt_lds[2 * VBUF];

    const int tid  = threadIdx.x;
    const int w    = tid >> 6;      // wave 0..7, owns q rows w*32..w*32+31
    const int lane = tid & 63;
    const int c32  = lane & 31;
    const int h    = lane >> 5;     // k-half within fragments
    const int msk8 = 8 * (c32 & 7); // read-side XOR mask (elems), K and V

    // bh->XCD grouping: 4 bh per XCD, streamed.
    const int wgid  = blockIdx.x;            // 0..511
    const int bh    = (wgid & 7) * 4 + (wgid >> 7);
    const int qtile = (wgid >> 3) & 15;
    const int qbase = qtile * QB;
    const float qscale = 0.08838834764831845f * 1.44269504088896341f;

    // ---- Q fragments (B-operand of swapped QK): col n = c32 = q-row,
    // k = ds*16 + h*8 + j ----
    const float* Qrow = Qg + ((size_t)bh * SQ + qbase + w * 32 + c32) * DH;
    ushort8 qf[8];
    #pragma unroll
    for (int ds = 0; ds < 8; ++ds) {
        floatv4 a = *(const floatv4*)(Qrow + ds * 16 + h * 8);
        floatv4 b = *(const floatv4*)(Qrow + ds * 16 + h * 8 + 4);
        uint4v u;
        u[0] = pk2(a[0]*qscale, a[1]*qscale);
        u[1] = pk2(a[2]*qscale, a[3]*qscale);
        u[2] = pk2(b[0]*qscale, b[1]*qscale);
        u[3] = pk2(b[2]*qscale, b[3]*qscale);
        qf[ds] = __builtin_bit_cast(ushort8, u);
    }

    f32x16 acc[4];
    #pragma unroll
    for (int i = 0; i < 4; ++i)
        #pragma unroll
        for (int r = 0; r < 16; ++r) acc[i][r] = 0.f;

    float l_run = 0.f;   // running denominator, m-hat = 0 domain

    const float* Kbh = Kg + (size_t)bh * SKV * DH;
    const float* Vbh = Vg + (size_t)bh * SKV * DH;

    // staging thread mappings (512 threads)
    const int n_k = tid >> 3;          // K row 0..63
    const int u_k = tid & 7;           // K 8-elem units {u_k, u_k+8}
    const int a_k = n_k & 7;           // K write XOR mask (units)
    const int nq  = tid & 15;          // V n-block (kv = 4*nq .. +3)   [NEW map]
    const int dq  = tid >> 4;          // V d-block (d = 4*dq .. +3) 0..31

    floatv4 ka0, ka1, kb0, kb1;        // K stage regs
    floatv4 va0, va1, va2, va3;        // V stage regs

#define LOAD_TILE(N0) do {                                                   \
        const float* ks_ = Kbh + (size_t)((N0) + n_k) * DH + u_k * 8;        \
        ka0 = *(const floatv4*)(ks_);        ka1 = *(const floatv4*)(ks_+4); \
        kb0 = *(const floatv4*)(ks_ + 64);   kb1 = *(const floatv4*)(ks_+68);\
        const float* vs_ = Vbh + (size_t)((N0) + nq * 4) * DH + dq * 4;      \
        va0 = *(const floatv4*)(vs_);        va1 = *(const floatv4*)(vs_+DH);\
        va2 = *(const floatv4*)(vs_+2*DH);   va3 = *(const floatv4*)(vs_+3*DH);\
    } while (0)

#define STORE_TILE(B) do {                                                   \
        unsigned short* kd_ = &K_lds[(B) * KBUF];                            \
        unsigned short* vd_ = &Vt_lds[(B) * VBUF];                           \
        uint4v u_;                                                           \
        u_[0]=pk2(ka0[0],ka0[1]); u_[1]=pk2(ka0[2],ka0[3]);                  \
        u_[2]=pk2(ka1[0],ka1[1]); u_[3]=pk2(ka1[2],ka1[3]);                  \
        *(uint4v*)&kd_[n_k * KROW + 8 * (u_k ^ a_k)] = u_;                   \
        u_[0]=pk2(kb0[0],kb0[1]); u_[1]=pk2(kb0[2],kb0[3]);                  \
        u_[2]=pk2(kb1[0],kb1[1]); u_[3]=pk2(kb1[2],kb1[3]);                  \
        *(uint4v*)&kd_[n_k * KROW + 8 * (u_k ^ a_k) + 64] = u_;              \
        _Pragma("unroll")                                                    \
        for (int i_ = 0; i_ < 4; ++i_) {                                     \
            const int d_ = dq * 4 + i_;                                      \
            uint2v p_;                                                       \
            p_[0] = pk2(va0[i_], va1[i_]);                                   \
            p_[1] = pk2(va2[i_], va3[i_]);                                   \
            *(uint2v*)&vd_[d_ * VROW + ((4 * nq) ^ (8 * (d_ & 7)))] = p_;    \
        }                                                                    \
    } while (0)

    // prologue: tile 0 -> buf0, tile 1 -> regs
    LOAD_TILE(0);
    STORE_TILE(0);
    LOAD_TILE(BN);
    __syncthreads();

    for (int t = 0; t < NT; ++t) {
        // stage t+1 into the idle buffer; prefetch t+2 into regs
        if (t + 1 < NT) {
            STORE_TILE((t + 1) & 1);
            if (t + 2 < NT) LOAD_TILE((size_t)(t + 2) * BN);
        }
        const unsigned short* Kb = &K_lds[(t & 1) * KBUF];
        const unsigned short* Vb = &Vt_lds[(t & 1) * VBUF];

        // ---- S = K Q^T (swapped, 32x32x16): C col = c32 = q,
        // row kv = ns*32 + (r&3)+8*(r>>2)+4*h ----
        f32x16 s[2];
        __builtin_amdgcn_s_setprio(1);
        #pragma unroll
        for (int ns = 0; ns < 2; ++ns) {
            f32x16 tt;
            #pragma unroll
            for (int r = 0; r < 16; ++r) tt[r] = 0.f;
            #pragma unroll
            for (int ds = 0; ds < 8; ++ds) {
                ushort8 kf = *(const ushort8*)&Kb[(ns * 32 + c32) * KROW
                                                  + ((ds * 16 + h * 8) ^ msk8)];
                tt = __builtin_amdgcn_mfma_f32_32x32x16_bf16(
                        __builtin_bit_cast(bf16x8, kf),
                        __builtin_bit_cast(bf16x8, qf[ds]), tt, 0, 0, 0);
            }
            s[ns] = tt;
        }
        __builtin_amdgcn_s_setprio(0);

        // ---- softmax, buggy variant, m-hat = 0 (p/l invariant to max) ----
        float ps = 0.f;
        #pragma unroll
        for (int ns = 0; ns < 2; ++ns) {
            #pragma unroll
            for (int r = 0; r < 16; ++r)
                s[ns][r] = __builtin_amdgcn_exp2f(s[ns][r]);
            float q0 = (s[ns][0]  + s[ns][1])  + (s[ns][2]  + s[ns][3]);
            float q1 = (s[ns][4]  + s[ns][5])  + (s[ns][6]  + s[ns][7]);
            float q2 = (s[ns][8]  + s[ns][9])  + (s[ns][10] + s[ns][11]);
            float q3 = (s[ns][12] + s[ns][13]) + (s[ns][14] + s[ns][15]);
            ps += (q0 + q1) + (q2 + q3);
        }
        ps += __shfl_xor(ps, 32);          // combine the two k-halves
        const float ln = l_run + ps;
        l_run = ln;
        const float inv = __builtin_amdgcn_rcpf(ln);

        // ---- pack P/l to bf16 words ----
        unsigned wrd[2][8];
        #pragma unroll
        for (int ns = 0; ns < 2; ++ns)
            #pragma unroll
            for (int i = 0; i < 8; ++i)
                wrd[ns][i] = pk2(s[ns][2*i] * inv, s[ns][2*i+1] * inv);

        // ---- redistribute to PV A-frags via two-input permlane32_swap ----
        ushort8 pa[4];
        #pragma unroll
        for (int step = 0; step < 4; ++step) {
            const int ns   = step >> 1;
            const int base = 4 * (step & 1);
            auto rA = __builtin_amdgcn_permlane32_swap(
                          (int)wrd[ns][base + 0], (int)wrd[ns][base + 2], false, false);
            auto rB = __builtin_amdgcn_permlane32_swap(
                          (int)wrd[ns][base + 1], (int)wrd[ns][base + 3], false, false);
            uint4v pw;
            pw[0] = (unsigned)rA[0];   // j0,1 : kv 16*step + 8h + {0,1}
            pw[1] = (unsigned)rB[0];   // j2,3
            pw[2] = (unsigned)rA[1];   // j4,5
            pw[3] = (unsigned)rB[1];   // j6,7
            pa[step] = __builtin_bit_cast(ushort8, pw);
        }

        // ---- PV (32x32x16): B col = c32 = d-local, k = 16*step + 8h + j;
        // Vt read: row d = dt*32+c32 (d&7 = c32&7), col 8*((2step+h)^msk) ----
        __builtin_amdgcn_s_setprio(1);
        #pragma unroll
        for (int dt = 0; dt < 4; ++dt) {
            const int d = dt * 32 + c32;
            #pragma unroll
            for (int step = 0; step < 4; ++step) {
                ushort8 vb = *(const ushort8*)&Vb[d * VROW
                                 + ((8 * (2 * step + h)) ^ msk8)];
                acc[dt] = __builtin_amdgcn_mfma_f32_32x32x16_bf16(
                    __builtin_bit_cast(bf16x8, pa[step]),
                    __builtin_bit_cast(bf16x8, vb), acc[dt], 0, 0, 0);
            }
        }
        __builtin_amdgcn_s_setprio(0);

        __syncthreads();   // tile t reads done everywhere; buf[(t+1)&1] ready
    }

    // ---- epilogue: PV C layout: col = c32 = d-local,
    // row q_local = (r&3) + 8*(r>>2) + 4*h ----
    float* ob = Og + ((size_t)bh * SQ + qbase + w * 32) * DH + c32;
    #pragma unroll
    for (int dt = 0; dt < 4; ++dt) {
        #pragma unroll
        for (int r = 0; r < 16; ++r) {
            const int qrow = (r & 3) + 8 * (r >> 2) + 4 * h;
            ob[(size_t)qrow * DH + dt * 32] = acc[dt][r];
        }
    }
}

extern "C" void kernel_launch(void* const* d_in, const int* in_sizes, int n_in,
                              void* d_out, int out_size, void* d_ws, size_t ws_size,
                              hipStream_t stream) {
    const float* q = (const float*)d_in[0];
    const float* k = (const float*)d_in[1];
    const float* v = (const float*)d_in[2];
    float* o = (float*)d_out;
    dim3 grid((SQ / QB) * 32);   // 512 WGs
    fa_fwd_buggy<<<grid, 512, 0, stream>>>(q, k, v, o);
}